// Round 4
// baseline (542.869 us; speedup 1.0000x reference)
//
#include <hip/hip_runtime.h>
#include <hip/hip_bf16.h>

// B=2,S=2048 -> T=4096 tokens, D=1024, H=2048, E=8, top_k=2
#define TOK 4096
#define DD 1024
#define HH 2048
#define NE 8
#define RTOT (TOK * 2)

typedef __attribute__((ext_vector_type(8))) short bf16x8;
typedef __attribute__((ext_vector_type(4))) float f32x4;

static __device__ __forceinline__ unsigned short f2bf(float f) {
  union { float f; unsigned int u; } v; v.f = f;
  unsigned int r = v.u + 0x7fffu + ((v.u >> 16) & 1u);
  return (unsigned short)(r >> 16);
}

// async global->LDS, 16B/lane; LDS dest = wave-uniform base + lane*16
static __device__ __forceinline__ void gload16(const unsigned short* g, unsigned short* l) {
  __builtin_amdgcn_global_load_lds(
      (const __attribute__((address_space(1))) unsigned int*)g,
      (__attribute__((address_space(3))) unsigned int*)l, 16, 0, 0);
}

#define WAITV0() asm volatile("s_waitcnt vmcnt(0)" ::: "memory")
// packed f32x2 -> bf16x2 (RNE), single HW instruction
#define CVT(d, lo, hi) asm("v_cvt_pk_bf16_f32 %0, %1, %2" : "=v"(d) : "v"(lo), "v"(hi))

// ---------------- router: fp32 scores, top-2 softmax; also emits Xb (bf16 x) ----------------
__global__ void router_k(const float* __restrict__ x, const float* __restrict__ gw,
                         unsigned short* __restrict__ xb,
                         int* __restrict__ topi, float* __restrict__ topp,
                         int* __restrict__ counts) {
  const int lane = threadIdx.x & 63;
  const int t = blockIdx.x * 4 + (threadIdx.x >> 6);
  const float4* xr = (const float4*)(x + (size_t)t * DD);
  unsigned int* xw = (unsigned int*)(xb + (size_t)t * DD);
  float acc[NE];
#pragma unroll
  for (int e = 0; e < NE; ++e) acc[e] = 0.f;
#pragma unroll
  for (int i = 0; i < 4; ++i) {
    const float4 xv = xr[i * 64 + lane];
    unsigned int p0, p1;
    CVT(p0, xv.x, xv.y);
    CVT(p1, xv.z, xv.w);
    xw[(i * 64 + lane) * 2] = p0;
    xw[(i * 64 + lane) * 2 + 1] = p1;
#pragma unroll
    for (int e = 0; e < NE; ++e) {
      const float4 gv = ((const float4*)(gw + (size_t)e * DD))[i * 64 + lane];
      acc[e] += xv.x * gv.x + xv.y * gv.y + xv.z * gv.z + xv.w * gv.w;
    }
  }
#pragma unroll
  for (int e = 0; e < NE; ++e)
#pragma unroll
    for (int s = 32; s > 0; s >>= 1) acc[e] += __shfl_xor(acc[e], s, 64);
  if (lane == 0) {
    int i0 = 0; float v0 = acc[0];
#pragma unroll
    for (int e = 1; e < NE; ++e) if (acc[e] > v0) { v0 = acc[e]; i0 = e; }
    int i1 = -1; float v1 = -1e30f;
#pragma unroll
    for (int e = 0; e < NE; ++e) if (e != i0 && acc[e] > v1) { v1 = acc[e]; i1 = e; }
    const float ex = __expf(v1 - v0);
    const float inv = 1.f / (1.f + ex);
    topi[t * 2] = i0; topi[t * 2 + 1] = i1;
    topp[t * 2] = inv; topp[t * 2 + 1] = ex * inv;
    atomicAdd(&counts[i0], 1); atomicAdd(&counts[i1], 1);
  }
}

// ---------------- scan / scatter ----------------
__global__ void scan_k(const int* __restrict__ counts, int* __restrict__ offsets,
                       int* __restrict__ cursor) {
  if (threadIdx.x == 0) {
    int s = 0;
    for (int e = 0; e < NE; ++e) { offsets[e] = s; cursor[e] = s; s += counts[e]; }
  }
}

__global__ void scatter_k(const int* __restrict__ topi, const float* __restrict__ topp,
                          int* __restrict__ cursor, int* __restrict__ perm,
                          float* __restrict__ prow, int* __restrict__ rowid) {
  const int t = blockIdx.x * 256 + threadIdx.x;
#pragma unroll
  for (int k = 0; k < 2; ++k) {
    const int e = topi[t * 2 + k];
    const int pos = atomicAdd(&cursor[e], 1);
    perm[pos] = t;
    prow[pos] = topp[t * 2 + k];
    rowid[t * 2 + k] = pos;
  }
}

// ---- shared GEMM staging macros (straight-line, register-resident) ----
#define LOADB(STRIDE)                                   \
  do {                                                  \
    b0 = *(const float4*)(pB);                          \
    b1 = *(const float4*)(pB + (STRIDE));               \
    b2 = *(const float4*)(pB + 2 * (STRIDE));           \
    b3 = *(const float4*)(pB + 3 * (STRIDE));           \
    b4 = *(const float4*)(pB + 4 * (STRIDE));           \
    b5 = *(const float4*)(pB + 5 * (STRIDE));           \
    b6 = *(const float4*)(pB + 6 * (STRIDE));           \
    b7 = *(const float4*)(pB + 7 * (STRIDE));           \
    pB += 64 * (STRIDE);                                \
  } while (0)

#define WRITEB(BOFF)                                                      \
  do {                                                                    \
    uint4 t0, t1, t2, t3;                                                 \
    CVT(t0.x, b0.x, b1.x); CVT(t0.y, b2.x, b3.x);                         \
    CVT(t0.z, b4.x, b5.x); CVT(t0.w, b6.x, b7.x);                         \
    CVT(t1.x, b0.y, b1.y); CVT(t1.y, b2.y, b3.y);                         \
    CVT(t1.z, b4.y, b5.y); CVT(t1.w, b6.y, b7.y);                         \
    CVT(t2.x, b0.z, b1.z); CVT(t2.y, b2.z, b3.z);                         \
    CVT(t2.z, b4.z, b5.z); CVT(t2.w, b6.z, b7.z);                         \
    CVT(t3.x, b0.w, b1.w); CVT(t3.y, b2.w, b3.w);                         \
    CVT(t3.z, b4.w, b5.w); CVT(t3.w, b6.w, b7.w);                         \
    *(uint4*)&lds[(BOFF) + bslot0] = t0;                                  \
    *(uint4*)&lds[(BOFF) + bslot1] = t1;                                  \
    *(uint4*)&lds[(BOFF) + bslot2] = t2;                                  \
    *(uint4*)&lds[(BOFF) + bslot3] = t3;                                  \
  } while (0)

#define ISSUEA(BB, NQ)                                                    \
  do {                                                                    \
    _Pragma("unroll")                                                     \
    for (int qq = 0; qq < (NQ); ++qq) {                                   \
      gload16(pA[qq], lds + (BB) * 8192 + (wv * 32 + qq * 8) * 64);       \
      pA[qq] += 64;                                                       \
    }                                                                     \
  } while (0)

#define COMPUTE(BB, NM)                                                   \
  do {                                                                    \
    const unsigned short* Ab = lds + (BB) * 8192;                         \
    const unsigned short* Bb = lds + 16384 + (BB) * 8192;                 \
    _Pragma("unroll")                                                     \
    for (int kk = 0; kk < 2; ++kk) {                                      \
      bf16x8 af[NM], bv[4];                                               \
      _Pragma("unroll")                                                   \
      for (int mf = 0; mf < (NM); ++mf)                                   \
        af[mf] = *(const bf16x8*)&Ab[(wr * 64 + mf * 16 + lr) * 64 +      \
                                     ((kk * 4 + kc) ^ (lr & 7)) * 8];     \
      _Pragma("unroll")                                                   \
      for (int nf = 0; nf < 4; ++nf) {                                    \
        const int rowb = wc * 64 + nf * 16 + lr;                          \
        bv[nf] = *(const bf16x8*)&Bb[rowb * 64 +                          \
              (((kk * 4 + kc) ^ (rowb & 7) ^ ((rowb >> 3) & 3)) * 8)];    \
      }                                                                   \
      _Pragma("unroll")                                                   \
      for (int mf = 0; mf < (NM); ++mf)                                   \
        _Pragma("unroll")                                                 \
        for (int nf = 0; nf < 4; ++nf)                                    \
          acc[mf][nf] = __builtin_amdgcn_mfma_f32_16x16x32_bf16(          \
              af[mf], bv[nf], acc[mf][nf], 0, 0, 0);                      \
    }                                                                     \
  } while (0)

// ---------------- GEMM1: X(gathered bf16) @ [w1|w2](fp32, cvt in-kernel) -> h ----------------
// BM=128, 64 h-cols (128 interleaved G/U LDS rows), BK=64, 4 waves (2Mx2N), dbuf LDS 64KB.
__global__ __launch_bounds__(256, 2) void gemm1_k(
    const unsigned short* __restrict__ Xb, const float* __restrict__ w1,
    const float* __restrict__ w2, const int* __restrict__ counts,
    const int* __restrict__ offsets, const int* __restrict__ perm,
    unsigned short* __restrict__ hbuf) {
  const int e = blockIdx.z;
  const int ne = counts[e];
  const int m0 = blockIdx.y * 128;
  if (m0 >= ne) return;
  const int off = offsets[e];
  const int jb = blockIdx.x * 64;

  extern __shared__ __align__(16) unsigned short lds[];  // A0 A1 B0 B1 x 16KB

  const int tid = threadIdx.x;
  const int lane = tid & 63, wv = tid >> 6;

  // A staging (wave wv: rows wv*32..+31)
  const int lrow8 = lane >> 3;
  const int schunk = ((lane & 7) ^ lrow8) * 8;
  const unsigned short* pA[4];
#pragma unroll
  for (int qq = 0; qq < 4; ++qq) {
    const int row = wv * 32 + qq * 8 + lrow8;
    pA[qq] = Xb + (size_t)perm[off + min(m0 + row, ne - 1)] * DD + schunk;
  }

  // B staging: thread -> LDS rows q*4..+3 (interleaved G/U 16-col groups), k-chunk c
  const int q = tid & 31, c = tid >> 5;
  const int mat = (q >> 2) & 1;
  const int hcol0 = jb + (q >> 3) * 16 + (q & 3) * 4;
  const float* pB = (mat ? w2 : w1) + ((size_t)e * DD + c * 8) * HH + hcol0;
  const int br0 = q * 4;
  const int bslot0 = (br0 + 0) * 64 + ((c ^ ((br0 + 0) & 7) ^ (((br0 + 0) >> 3) & 3)) * 8);
  const int bslot1 = (br0 + 1) * 64 + ((c ^ ((br0 + 1) & 7) ^ (((br0 + 1) >> 3) & 3)) * 8);
  const int bslot2 = (br0 + 2) * 64 + ((c ^ ((br0 + 2) & 7) ^ (((br0 + 2) >> 3) & 3)) * 8);
  const int bslot3 = (br0 + 3) * 64 + ((c ^ ((br0 + 3) & 7) ^ (((br0 + 3) >> 3) & 3)) * 8);

  const int wr = wv >> 1, wc = wv & 1;
  const int lr = lane & 15, kc = lane >> 4;

  f32x4 acc[4][4];
#pragma unroll
  for (int a = 0; a < 4; ++a)
#pragma unroll
    for (int b = 0; b < 4; ++b) acc[a][b] = f32x4{0.f, 0.f, 0.f, 0.f};

  float4 b0, b1, b2, b3, b4, b5, b6, b7;

  LOADB(HH);
  ISSUEA(0, 4);
  WAITV0();
  WRITEB(16384);
  __syncthreads();
  for (int t = 0; t < DD / 64 - 1; ++t) {
    const int cur = t & 1, nxt = cur ^ 1;
    LOADB(HH);
    ISSUEA(nxt, 4);
    COMPUTE(cur, 4);
    WAITV0();
    WRITEB(16384 + nxt * 8192);
    __syncthreads();
  }
  COMPUTE((DD / 64 - 1) & 1, 4);

  // epilogue: silu(g)*u -> hbuf
#pragma unroll
  for (int mf = 0; mf < 4; ++mf)
#pragma unroll
    for (int pp = 0; pp < 2; ++pp) {
      const f32x4 g = acc[mf][2 * pp], u = acc[mf][2 * pp + 1];
      const int hcol = jb + (wc * 2 + pp) * 16 + lr;
#pragma unroll
      for (int r = 0; r < 4; ++r) {
        const int rl = m0 + wr * 64 + mf * 16 + kc * 4 + r;
        if (rl < ne) {
          const float gg = g[r], uu = u[r];
          const float hv = gg / (1.f + __expf(-gg)) * uu;
          hbuf[(size_t)(off + rl) * HH + hcol] = f2bf(hv);
        }
      }
    }
}

// ---------------- GEMM2: h(bf16) @ w3(fp32, cvt in-kernel) * prob -> y fp32 ----------------
// BM=128, BN=128, BK=64, 4 waves (2Mx2N), dbuf LDS 64KB, K=2048.
__global__ __launch_bounds__(256, 2) void gemm2_k(
    const unsigned short* __restrict__ hbuf, const float* __restrict__ w3,
    const int* __restrict__ counts, const int* __restrict__ offsets,
    const float* __restrict__ prow, float* __restrict__ ybuf) {
  const int e = blockIdx.z;
  const int ne = counts[e];
  const int m0 = blockIdx.y * 128;
  if (m0 >= ne) return;
  const int off = offsets[e];
  const int n1 = blockIdx.x * 128;

  extern __shared__ __align__(16) unsigned short lds[];

  const int tid = threadIdx.x;
  const int lane = tid & 63, wv = tid >> 6;

  const int lrow8 = lane >> 3;
  const int schunk = ((lane & 7) ^ lrow8) * 8;
  const unsigned short* pA[4];
#pragma unroll
  for (int qq = 0; qq < 4; ++qq) {
    const int row = wv * 32 + qq * 8 + lrow8;
    pA[qq] = hbuf + (size_t)(off + min(m0 + row, ne - 1)) * HH + schunk;
  }

  const int q = tid & 31, c = tid >> 5;
  const float* pB = w3 + ((size_t)e * HH + c * 8) * DD + n1 + q * 4;
  const int br0 = q * 4;
  const int bslot0 = (br0 + 0) * 64 + ((c ^ ((br0 + 0) & 7) ^ (((br0 + 0) >> 3) & 3)) * 8);
  const int bslot1 = (br0 + 1) * 64 + ((c ^ ((br0 + 1) & 7) ^ (((br0 + 1) >> 3) & 3)) * 8);
  const int bslot2 = (br0 + 2) * 64 + ((c ^ ((br0 + 2) & 7) ^ (((br0 + 2) >> 3) & 3)) * 8);
  const int bslot3 = (br0 + 3) * 64 + ((c ^ ((br0 + 3) & 7) ^ (((br0 + 3) >> 3) & 3)) * 8);

  const int wr = wv >> 1, wc = wv & 1;
  const int lr = lane & 15, kc = lane >> 4;

  f32x4 acc[4][4];
#pragma unroll
  for (int a = 0; a < 4; ++a)
#pragma unroll
    for (int b = 0; b < 4; ++b) acc[a][b] = f32x4{0.f, 0.f, 0.f, 0.f};

  float4 b0, b1, b2, b3, b4, b5, b6, b7;

  LOADB(DD);
  ISSUEA(0, 4);
  WAITV0();
  WRITEB(16384);
  __syncthreads();
  for (int t = 0; t < HH / 64 - 1; ++t) {
    const int cur = t & 1, nxt = cur ^ 1;
    LOADB(DD);
    ISSUEA(nxt, 4);
    COMPUTE(cur, 4);
    WAITV0();
    WRITEB(16384 + nxt * 8192);
    __syncthreads();
  }
  COMPUTE((HH / 64 - 1) & 1, 4);

#pragma unroll
  for (int mf = 0; mf < 4; ++mf)
#pragma unroll
    for (int nf = 0; nf < 4; ++nf)
#pragma unroll
      for (int r = 0; r < 4; ++r) {
        const int rl = m0 + wr * 64 + mf * 16 + kc * 4 + r;
        if (rl < ne) {
          ybuf[(size_t)(off + rl) * DD + n1 + wc * 64 + nf * 16 + lr] =
              prow[off + rl] * acc[mf][nf][r];
        }
      }
}

// ---------------- combine ----------------
__global__ void combine_k(const float* __restrict__ y, const int* __restrict__ rowid,
                          float* __restrict__ out) {
  const int i = blockIdx.x * 256 + threadIdx.x;
  const int t = i >> 8;
  const float4 a = ((const float4*)(y + (size_t)rowid[2 * t] * DD))[i & 255];
  const float4 b = ((const float4*)(y + (size_t)rowid[2 * t + 1] * DD))[i & 255];
  float4 o; o.x = a.x + b.x; o.y = a.y + b.y; o.z = a.z + b.z; o.w = a.w + b.w;
  ((float4*)out)[i] = o;
}

// ---------------- workspace layout ----------------
#define WS_COUNTS 0
#define WS_OFFS 32
#define WS_CURS 64
#define WS_TOPI 128
#define WS_TOPP (WS_TOPI + TOK * 2 * 4)
#define WS_ROWID (WS_TOPP + TOK * 2 * 4)
#define WS_PERM (WS_ROWID + TOK * 2 * 4)
#define WS_PROW (WS_PERM + RTOT * 4)
#define WS_XB ((WS_PROW + RTOT * 4 + 255) & ~(size_t)255)
#define WS_H (WS_XB + (size_t)TOK * DD * 2)
#define WS_Y (WS_H + (size_t)RTOT * HH * 2)
// end = WS_Y + RTOT*DD*4 ~= 73 MB

extern "C" void kernel_launch(void* const* d_in, const int* in_sizes, int n_in,
                              void* d_out, int out_size, void* d_ws, size_t ws_size,
                              hipStream_t stream) {
  const float* x = (const float*)d_in[0];
  const float* gw = (const float*)d_in[1];
  const float* w1 = (const float*)d_in[2];
  const float* w2 = (const float*)d_in[3];
  const float* w3 = (const float*)d_in[4];
  float* out = (float*)d_out;
  char* ws = (char*)d_ws;

  int* counts = (int*)(ws + WS_COUNTS);
  int* offsets = (int*)(ws + WS_OFFS);
  int* cursor = (int*)(ws + WS_CURS);
  int* topi = (int*)(ws + WS_TOPI);
  float* topp = (float*)(ws + WS_TOPP);
  int* rowid = (int*)(ws + WS_ROWID);
  int* perm = (int*)(ws + WS_PERM);
  float* prow = (float*)(ws + WS_PROW);
  unsigned short* Xb = (unsigned short*)(ws + WS_XB);
  unsigned short* hbuf = (unsigned short*)(ws + WS_H);
  float* ybuf = (float*)(ws + WS_Y);

  hipFuncSetAttribute((const void*)gemm1_k, hipFuncAttributeMaxDynamicSharedMemorySize, 65536);
  hipFuncSetAttribute((const void*)gemm2_k, hipFuncAttributeMaxDynamicSharedMemorySize, 65536);

  hipMemsetAsync(ws, 0, 128, stream);
  router_k<<<TOK / 4, 256, 0, stream>>>(x, gw, Xb, topi, topp, counts);
  scan_k<<<1, 64, 0, stream>>>(counts, offsets, cursor);
  scatter_k<<<TOK / 256, 256, 0, stream>>>(topi, topp, cursor, perm, prow, rowid);
  gemm1_k<<<dim3(HH / 64, RTOT / 128, NE), 256, 65536, stream>>>(
      Xb, w1, w2, counts, offsets, perm, hbuf);
  gemm2_k<<<dim3(DD / 128, RTOT / 128, NE), 256, 65536, stream>>>(
      hbuf, w3, counts, offsets, prow, ybuf);
  combine_k<<<TOK * DD / 4 / 256, 256, 0, stream>>>(ybuf, rowid, out);
}

// Round 5
// 382.749 us; speedup vs baseline: 1.4183x; 1.4183x over previous
//
#include <hip/hip_runtime.h>
#include <hip/hip_bf16.h>

// B=2,S=2048 -> T=4096 tokens, D=1024, H=2048, E=8, top_k=2
#define TOK 4096
#define DD 1024
#define HH 2048
#define NE 8
#define RTOT (TOK * 2)

typedef __attribute__((ext_vector_type(8))) short bf16x8;
typedef __attribute__((ext_vector_type(4))) float f32x4;

static __device__ __forceinline__ unsigned short f2bf(float f) {
  union { float f; unsigned int u; } v; v.f = f;
  unsigned int r = v.u + 0x7fffu + ((v.u >> 16) & 1u);
  return (unsigned short)(r >> 16);
}

// async global->LDS, 16B/lane; LDS dest = wave-uniform base + lane*16
static __device__ __forceinline__ void gload16(const unsigned short* g, unsigned short* l) {
  __builtin_amdgcn_global_load_lds(
      (const __attribute__((address_space(1))) unsigned int*)g,
      (__attribute__((address_space(3))) unsigned int*)l, 16, 0, 0);
}

// packed f32x2 -> bf16x2 (RNE), single HW instruction
#define CVT(d, lo, hi) asm("v_cvt_pk_bf16_f32 %0, %1, %2" : "=v"(d) : "v"(lo), "v"(hi))

// ---------------- router: fp32 scores, top-2 softmax; also emits Xb (bf16 x) ----------------
__global__ void router_k(const float* __restrict__ x, const float* __restrict__ gw,
                         unsigned short* __restrict__ xb,
                         int* __restrict__ topi, float* __restrict__ topp,
                         int* __restrict__ counts) {
  const int lane = threadIdx.x & 63;
  const int t = blockIdx.x * 4 + (threadIdx.x >> 6);
  const float4* xr = (const float4*)(x + (size_t)t * DD);
  unsigned int* xw = (unsigned int*)(xb + (size_t)t * DD);
  float acc[NE];
#pragma unroll
  for (int e = 0; e < NE; ++e) acc[e] = 0.f;
#pragma unroll
  for (int i = 0; i < 4; ++i) {
    const float4 xv = xr[i * 64 + lane];
    unsigned int p0, p1;
    CVT(p0, xv.x, xv.y);
    CVT(p1, xv.z, xv.w);
    xw[(i * 64 + lane) * 2] = p0;
    xw[(i * 64 + lane) * 2 + 1] = p1;
#pragma unroll
    for (int e = 0; e < NE; ++e) {
      const float4 gv = ((const float4*)(gw + (size_t)e * DD))[i * 64 + lane];
      acc[e] += xv.x * gv.x + xv.y * gv.y + xv.z * gv.z + xv.w * gv.w;
    }
  }
#pragma unroll
  for (int e = 0; e < NE; ++e)
#pragma unroll
    for (int s = 32; s > 0; s >>= 1) acc[e] += __shfl_xor(acc[e], s, 64);
  if (lane == 0) {
    int i0 = 0; float v0 = acc[0];
#pragma unroll
    for (int e = 1; e < NE; ++e) if (acc[e] > v0) { v0 = acc[e]; i0 = e; }
    int i1 = -1; float v1 = -1e30f;
#pragma unroll
    for (int e = 0; e < NE; ++e) if (e != i0 && acc[e] > v1) { v1 = acc[e]; i1 = e; }
    const float ex = __expf(v1 - v0);
    const float inv = 1.f / (1.f + ex);
    topi[t * 2] = i0; topi[t * 2 + 1] = i1;
    topp[t * 2] = inv; topp[t * 2 + 1] = ex * inv;
    atomicAdd(&counts[i0], 1); atomicAdd(&counts[i1], 1);
  }
}

// ---------------- weight transpose+convert ----------------
// mat 0/1: w1/w2 [D][H] fp32 -> wgu bf16 [2H][D] with 16-col G/U groups interleaved:
//   hcol j of w1 -> row ((j>>4)<<5)+(j&15); of w2 -> same + 16.
// mat 2: w3 [H][D] fp32 -> w3t bf16 [D][H].
__global__ __launch_bounds__(256) void transpose_k(
    const float* __restrict__ w1, const float* __restrict__ w2, const float* __restrict__ w3,
    unsigned short* __restrict__ wgu, unsigned short* __restrict__ w3t) {
  const int z = blockIdx.y;
  const int mat = z >> 3, e = z & 7;
  __shared__ unsigned short t[64 * 72];
  const int tid = threadIdx.x;
  const int lane = tid & 63, wv = tid >> 6;

  if (mat < 2) {
    const float* in = (mat ? w2 : w1) + (size_t)e * DD * HH;
    const int tc = blockIdx.x & 31, tr = blockIdx.x >> 5;   // 32 col-tiles, 16 row-tiles
    const int c0 = tc * 64, r0 = tr * 64;
#pragma unroll
    for (int p = 0; p < 4; ++p) {
      const int rb = (wv * 4 + p) * 4;
      ushort4 o;
      o.x = f2bf(in[(size_t)(r0 + rb + 0) * HH + c0 + lane]);
      o.y = f2bf(in[(size_t)(r0 + rb + 1) * HH + c0 + lane]);
      o.z = f2bf(in[(size_t)(r0 + rb + 2) * HH + c0 + lane]);
      o.w = f2bf(in[(size_t)(r0 + rb + 3) * HH + c0 + lane]);
      *(ushort4*)&t[lane * 72 + rb] = o;
    }
    __syncthreads();
#pragma unroll
    for (int q = 0; q < 2; ++q) {
      const int idx = q * 256 + tid;
      const int crow = idx >> 3, seg = idx & 7;
      const int j = c0 + crow;
      const int R = ((j >> 4) << 5) + (j & 15) + mat * 16;
      *(uint4*)&wgu[((size_t)e * 2 * HH + R) * DD + r0 + seg * 8] =
          *(const uint4*)&t[crow * 72 + seg * 8];
    }
  } else {
    const float* in = w3 + (size_t)e * HH * DD;
    const int tc = blockIdx.x & 15, tr = blockIdx.x >> 4;   // 16 col-tiles, 32 row-tiles
    const int c0 = tc * 64, r0 = tr * 64;
#pragma unroll
    for (int p = 0; p < 4; ++p) {
      const int rb = (wv * 4 + p) * 4;
      ushort4 o;
      o.x = f2bf(in[(size_t)(r0 + rb + 0) * DD + c0 + lane]);
      o.y = f2bf(in[(size_t)(r0 + rb + 1) * DD + c0 + lane]);
      o.z = f2bf(in[(size_t)(r0 + rb + 2) * DD + c0 + lane]);
      o.w = f2bf(in[(size_t)(r0 + rb + 3) * DD + c0 + lane]);
      *(ushort4*)&t[lane * 72 + rb] = o;
    }
    __syncthreads();
#pragma unroll
    for (int q = 0; q < 2; ++q) {
      const int idx = q * 256 + tid;
      const int crow = idx >> 3, seg = idx & 7;
      *(uint4*)&w3t[((size_t)e * DD + c0 + crow) * HH + r0 + seg * 8] =
          *(const uint4*)&t[crow * 72 + seg * 8];
    }
  }
}

// ---------------- scan / scatter ----------------
__global__ void scan_k(const int* __restrict__ counts, int* __restrict__ offsets,
                       int* __restrict__ cursor) {
  if (threadIdx.x == 0) {
    int s = 0;
    for (int e = 0; e < NE; ++e) { offsets[e] = s; cursor[e] = s; s += counts[e]; }
  }
}

__global__ void scatter_k(const int* __restrict__ topi, const float* __restrict__ topp,
                          int* __restrict__ cursor, int* __restrict__ perm,
                          float* __restrict__ prow, int* __restrict__ rowid) {
  const int t = blockIdx.x * 256 + threadIdx.x;
#pragma unroll
  for (int k = 0; k < 2; ++k) {
    const int e = topi[t * 2 + k];
    const int pos = atomicAdd(&cursor[e], 1);
    perm[pos] = t;
    prow[pos] = topp[t * 2 + k];
    rowid[t * 2 + k] = pos;
  }
}

// ---------------- GEMM1: X(gathered bf16) @ wgu(bf16) -> h = silu(g)*u ----------------
// m97 structure: BM=128, BN=128 (interleaved G/U), BK=64, 4 waves (2x2), single-buffer LDS.
__global__ __launch_bounds__(256) void gemm1_k(
    const unsigned short* __restrict__ Xb, const unsigned short* __restrict__ wgu,
    const int* __restrict__ counts, const int* __restrict__ offsets,
    const int* __restrict__ perm, unsigned short* __restrict__ hbuf) {
  const int e = blockIdx.z, ne = counts[e];
  const int m0 = blockIdx.y * 128;
  if (m0 >= ne) return;
  const int off = offsets[e];
  const int bx = blockIdx.x;           // 64 h-cols per block

  __shared__ unsigned short As[128 * 64];
  __shared__ unsigned short Bs[128 * 64];

  const int tid = threadIdx.x, lane = tid & 63, wv = tid >> 6;
  const int srow = lane >> 3;
  const int schunk = ((lane & 7) ^ srow) * 8;

  const unsigned short* pA[4];
  const unsigned short* pB[4];
#pragma unroll
  for (int q = 0; q < 4; ++q) {
    const int row = wv * 32 + q * 8 + srow;
    pA[q] = Xb + (size_t)perm[off + min(m0 + row, ne - 1)] * DD + schunk;
    pB[q] = wgu + ((size_t)e * 2 * HH + bx * 128 + row) * DD + schunk;
  }

  const int wr = wv >> 1, wc = wv & 1;
  const int lr = lane & 15, kc = lane >> 4;

  f32x4 acc[4][4];
#pragma unroll
  for (int a = 0; a < 4; ++a)
#pragma unroll
    for (int b = 0; b < 4; ++b) acc[a][b] = f32x4{0.f, 0.f, 0.f, 0.f};

  for (int t = 0; t < DD / 64; ++t) {
#pragma unroll
    for (int q = 0; q < 4; ++q) {
      gload16(pA[q], &As[(wv * 32 + q * 8) * 64]); pA[q] += 64;
      gload16(pB[q], &Bs[(wv * 32 + q * 8) * 64]); pB[q] += 64;
    }
    __syncthreads();
#pragma unroll
    for (int kk = 0; kk < 2; ++kk) {
      bf16x8 af[4], bf[4];
#pragma unroll
      for (int mf = 0; mf < 4; ++mf)
        af[mf] = *(const bf16x8*)&As[(wr * 64 + mf * 16 + lr) * 64 + ((kk * 4 + kc) ^ (lr & 7)) * 8];
#pragma unroll
      for (int nf = 0; nf < 4; ++nf)
        bf[nf] = *(const bf16x8*)&Bs[(wc * 64 + nf * 16 + lr) * 64 + ((kk * 4 + kc) ^ (lr & 7)) * 8];
#pragma unroll
      for (int mf = 0; mf < 4; ++mf)
#pragma unroll
        for (int nf = 0; nf < 4; ++nf)
          acc[mf][nf] = __builtin_amdgcn_mfma_f32_16x16x32_bf16(af[mf], bf[nf], acc[mf][nf], 0, 0, 0);
    }
    __syncthreads();
  }

  // epilogue: nf even = G, nf odd = U (same 16 h-cols)
#pragma unroll
  for (int mf = 0; mf < 4; ++mf)
#pragma unroll
    for (int np = 0; np < 2; ++np) {
      const f32x4 g = acc[mf][2 * np], u = acc[mf][2 * np + 1];
      const int hcol = bx * 64 + (wc * 2 + np) * 16 + lr;
#pragma unroll
      for (int r = 0; r < 4; ++r) {
        const int rl = m0 + wr * 64 + mf * 16 + kc * 4 + r;
        if (rl < ne) {
          const float gg = g[r], uu = u[r];
          const float hv = gg / (1.f + __expf(-gg)) * uu;
          hbuf[(size_t)(off + rl) * HH + hcol] = f2bf(hv);
        }
      }
    }
}

// ---------------- GEMM2: h(bf16) @ w3t(bf16) * prob -> y fp32 ----------------
// BM=128, BN=128, BK=64, 4 waves (2x2), single-buffer LDS, K=2048.
__global__ __launch_bounds__(256) void gemm2_k(
    const unsigned short* __restrict__ hbuf, const unsigned short* __restrict__ w3t,
    const int* __restrict__ counts, const int* __restrict__ offsets,
    const float* __restrict__ prow, float* __restrict__ ybuf) {
  const int e = blockIdx.z, ne = counts[e];
  const int m0 = blockIdx.y * 128;
  if (m0 >= ne) return;
  const int off = offsets[e];
  const int n1 = blockIdx.x * 128;

  __shared__ unsigned short As[128 * 64];
  __shared__ unsigned short Bs[128 * 64];

  const int tid = threadIdx.x, lane = tid & 63, wv = tid >> 6;
  const int srow = lane >> 3;
  const int schunk = ((lane & 7) ^ srow) * 8;

  const unsigned short* pA[4];
  const unsigned short* pB[4];
#pragma unroll
  for (int q = 0; q < 4; ++q) {
    const int row = wv * 32 + q * 8 + srow;
    pA[q] = hbuf + (size_t)(off + min(m0 + row, ne - 1)) * HH + schunk;
    pB[q] = w3t + ((size_t)e * DD + n1 + row) * HH + schunk;
  }

  const int wr = wv >> 1, wc = wv & 1;
  const int lr = lane & 15, kc = lane >> 4;

  f32x4 acc[4][4];
#pragma unroll
  for (int a = 0; a < 4; ++a)
#pragma unroll
    for (int b = 0; b < 4; ++b) acc[a][b] = f32x4{0.f, 0.f, 0.f, 0.f};

  for (int t = 0; t < HH / 64; ++t) {
#pragma unroll
    for (int q = 0; q < 4; ++q) {
      gload16(pA[q], &As[(wv * 32 + q * 8) * 64]); pA[q] += 64;
      gload16(pB[q], &Bs[(wv * 32 + q * 8) * 64]); pB[q] += 64;
    }
    __syncthreads();
#pragma unroll
    for (int kk = 0; kk < 2; ++kk) {
      bf16x8 af[4], bf[4];
#pragma unroll
      for (int mf = 0; mf < 4; ++mf)
        af[mf] = *(const bf16x8*)&As[(wr * 64 + mf * 16 + lr) * 64 + ((kk * 4 + kc) ^ (lr & 7)) * 8];
#pragma unroll
      for (int nf = 0; nf < 4; ++nf)
        bf[nf] = *(const bf16x8*)&Bs[(wc * 64 + nf * 16 + lr) * 64 + ((kk * 4 + kc) ^ (lr & 7)) * 8];
#pragma unroll
      for (int mf = 0; mf < 4; ++mf)
#pragma unroll
        for (int nf = 0; nf < 4; ++nf)
          acc[mf][nf] = __builtin_amdgcn_mfma_f32_16x16x32_bf16(af[mf], bf[nf], acc[mf][nf], 0, 0, 0);
    }
    __syncthreads();
  }

#pragma unroll
  for (int mf = 0; mf < 4; ++mf)
#pragma unroll
    for (int nf = 0; nf < 4; ++nf)
#pragma unroll
      for (int r = 0; r < 4; ++r) {
        const int rl = m0 + wr * 64 + mf * 16 + kc * 4 + r;
        if (rl < ne) {
          ybuf[(size_t)(off + rl) * DD + n1 + wc * 64 + nf * 16 + lr] =
              prow[off + rl] * acc[mf][nf][r];
        }
      }
}

// ---------------- combine ----------------
__global__ void combine_k(const float* __restrict__ y, const int* __restrict__ rowid,
                          float* __restrict__ out) {
  const int i = blockIdx.x * 256 + threadIdx.x;
  const int t = i >> 8;
  const float4 a = ((const float4*)(y + (size_t)rowid[2 * t] * DD))[i & 255];
  const float4 b = ((const float4*)(y + (size_t)rowid[2 * t + 1] * DD))[i & 255];
  float4 o; o.x = a.x + b.x; o.y = a.y + b.y; o.z = a.z + b.z; o.w = a.w + b.w;
  ((float4*)out)[i] = o;
}

// ---------------- workspace layout ----------------
#define WS_COUNTS 0
#define WS_OFFS 32
#define WS_CURS 64
#define WS_TOPI 128
#define WS_TOPP (WS_TOPI + TOK * 2 * 4)
#define WS_ROWID (WS_TOPP + TOK * 2 * 4)
#define WS_PERM (WS_ROWID + TOK * 2 * 4)
#define WS_PROW (WS_PERM + RTOT * 4)
#define WS_XB ((WS_PROW + RTOT * 4 + 255) & ~(size_t)255)
#define WS_H (WS_XB + (size_t)TOK * DD * 2)
#define WS_WGU (WS_H + (size_t)RTOT * HH * 2)
#define WS_W3T (WS_WGU + (size_t)NE * 2 * HH * DD * 2)
#define WS_Y WS_WGU   // ybuf (32MB) aliases wgu (64MB, dead after gemm1)
// end = WS_W3T + NE*DD*HH*2 ~= 136 MB

extern "C" void kernel_launch(void* const* d_in, const int* in_sizes, int n_in,
                              void* d_out, int out_size, void* d_ws, size_t ws_size,
                              hipStream_t stream) {
  const float* x = (const float*)d_in[0];
  const float* gw = (const float*)d_in[1];
  const float* w1 = (const float*)d_in[2];
  const float* w2 = (const float*)d_in[3];
  const float* w3 = (const float*)d_in[4];
  float* out = (float*)d_out;
  char* ws = (char*)d_ws;

  int* counts = (int*)(ws + WS_COUNTS);
  int* offsets = (int*)(ws + WS_OFFS);
  int* cursor = (int*)(ws + WS_CURS);
  int* topi = (int*)(ws + WS_TOPI);
  float* topp = (float*)(ws + WS_TOPP);
  int* rowid = (int*)(ws + WS_ROWID);
  int* perm = (int*)(ws + WS_PERM);
  float* prow = (float*)(ws + WS_PROW);
  unsigned short* Xb = (unsigned short*)(ws + WS_XB);
  unsigned short* hbuf = (unsigned short*)(ws + WS_H);
  unsigned short* wgu = (unsigned short*)(ws + WS_WGU);
  unsigned short* w3t = (unsigned short*)(ws + WS_W3T);
  float* ybuf = (float*)(ws + WS_Y);

  hipMemsetAsync(ws, 0, 128, stream);
  router_k<<<TOK / 4, 256, 0, stream>>>(x, gw, Xb, topi, topp, counts);
  transpose_k<<<dim3(512, 24), 256, 0, stream>>>(w1, w2, w3, wgu, w3t);
  scan_k<<<1, 64, 0, stream>>>(counts, offsets, cursor);
  scatter_k<<<TOK / 256, 256, 0, stream>>>(topi, topp, cursor, perm, prow, rowid);
  gemm1_k<<<dim3(2 * HH / 128, RTOT / 128, NE), 256, 0, stream>>>(
      Xb, wgu, counts, offsets, perm, hbuf);
  gemm2_k<<<dim3(DD / 128, RTOT / 128, NE), 256, 0, stream>>>(
      hbuf, w3t, counts, offsets, prow, ybuf);
  combine_k<<<TOK * DD / 4 / 256, 256, 0, stream>>>(ybuf, rowid, out);
}